// Round 1
// baseline (492.268 us; speedup 1.0000x reference)
//
#include <hip/hip_runtime.h>
#include <cstdint>
#include <cstddef>

// GAT layer, N=8192, F_in=512, F_out=64, fp32 in/out, int32 adjacency.
//
// Fused flash-style plan (never materialize the 8192x8192 intermediates):
//   k_wh     : Wh = h@W  [N,64];  wh1[i]=Wh[i].a1, wh2[i]=Wh[i].a2
//   k_mrow   : Mw2 = max_j wh2[j];  M[i] = leakyrelu(wh1[i]+Mw2)  (safe rowmax bound,
//              leakyrelu monotone => M[i] >= true row max; softmax shift-invariant)
//   k_attend : per row i, stream j: p = adj ? exp(lrelu(wh1[i]+wh2[j]) - M[i]) : 0
//              l_i += p ; o_i += p * Wh[j]   (4-way j-split partials in ws)
//   k_merge  : out = (sum_y o)/(sum_y l)
//
// ws usage: 2,678,784 floats = 10.3 MiB.

#define GAT_N    8192
#define GAT_FIN  512
#define GAT_F    64
#define TJ       64
#define JSPLIT   4
#define JCHUNK   (GAT_N / JSPLIT)     // 2048
#define NTILES   (JCHUNK / TJ)        // 32

__device__ __forceinline__ float lrelu(float x) { return x > 0.f ? x : 0.2f * x; }

// ---------------------------------------------------------------- kernel 1
// grid 512, block 256: 16 rows/block, thread = (row 0..15, f-quad 0..15)
__global__ __launch_bounds__(256) void k_wh(
    const float* __restrict__ h, const float* __restrict__ W,
    const float* __restrict__ a,
    float* __restrict__ Wh, float* __restrict__ wh1, float* __restrict__ wh2)
{
    __shared__ float sh[16 * 516];            // +4 pad: rows 4 banks apart
    const int tid = threadIdx.x;
    const size_t r0 = (size_t)blockIdx.x * 16;

    const float4* __restrict__ hsrc = (const float4*)(h + r0 * GAT_FIN);
#pragma unroll
    for (int c = 0; c < 8; ++c) {
        int idx = tid + c * 256;              // float4 index 0..2047
        int row = idx >> 7;                   // 128 float4 per row
        int c4  = idx & 127;
        *(float4*)&sh[row * 516 + c4 * 4] = hsrc[idx];
    }
    __syncthreads();

    const int row = tid >> 4;
    const int f4  = (tid & 15) * 4;
    float4 acc = make_float4(0.f, 0.f, 0.f, 0.f);
    const float* shr = &sh[row * 516];
#pragma unroll 8
    for (int k = 0; k < GAT_FIN; ++k) {
        float4 wv = *(const float4*)&W[k * GAT_F + f4];
        float hv = shr[k];
        acc.x += hv * wv.x; acc.y += hv * wv.y;
        acc.z += hv * wv.z; acc.w += hv * wv.w;
    }
    *(float4*)&Wh[(r0 + row) * GAT_F + f4] = acc;

    float4 a1 = *(const float4*)&a[f4];
    float4 a2 = *(const float4*)&a[GAT_F + f4];
    float pa = acc.x*a1.x + acc.y*a1.y + acc.z*a1.z + acc.w*a1.w;
    float pb = acc.x*a2.x + acc.y*a2.y + acc.z*a2.z + acc.w*a2.w;
#pragma unroll
    for (int m = 1; m < 16; m <<= 1) {
        pa += __shfl_xor(pa, m);
        pb += __shfl_xor(pb, m);
    }
    if ((tid & 15) == 0) { wh1[r0 + row] = pa; wh2[r0 + row] = pb; }
}

// ---------------------------------------------------------------- kernel 2
// single block: global max of wh2, then M[i] = lrelu(wh1[i] + Mw2)
__global__ __launch_bounds__(256) void k_mrow(
    const float* __restrict__ wh1, const float* __restrict__ wh2,
    float* __restrict__ M)
{
    __shared__ float red[256];
    const int tid = threadIdx.x;
    float mx = -3.4e38f;
#pragma unroll
    for (int c = 0; c < GAT_N / 256; ++c) mx = fmaxf(mx, wh2[tid + c * 256]);
    red[tid] = mx;
    __syncthreads();
    for (int s = 128; s > 0; s >>= 1) {
        if (tid < s) red[tid] = fmaxf(red[tid], red[tid + s]);
        __syncthreads();
    }
    const float Mw2 = red[0];
#pragma unroll
    for (int c = 0; c < GAT_N / 256; ++c) {
        int i = tid + c * 256;
        M[i] = lrelu(wh1[i] + Mw2);
    }
}

// ---------------------------------------------------------------- kernel 3
// grid (256, 4), block 256 (4 waves). Block: 32 rows x 2048-j chunk.
// Wave owns 8 rows. Per 64-j tile:
//   phase A (lane = (rowpair 0..3, j-quad 0..15)): p -> sP (wave-private)
//   phase B (lane = (rowgroup g, f-pair fp)):      o[4 rows][f2] += P @ sWh
__global__ __launch_bounds__(256) void k_attend(
    const int* __restrict__ adj, const float* __restrict__ Wh,
    const float* __restrict__ wh1, const float* __restrict__ wh2,
    const float* __restrict__ M,
    float* __restrict__ po, float* __restrict__ pl)
{
    __shared__ float sWh[2][TJ * GAT_F];      // 2 x 16 KB, double-buffered
    __shared__ float sP[4][8][TJ];            // per-wave P tile, 8 KB

    const int tid  = threadIdx.x;
    const int w    = tid >> 6;
    const int lane = tid & 63;
    const int rw   = blockIdx.x * 32 + w * 8; // wave's 8 rows
    const int j0   = blockIdx.y * JCHUNK;

    // phase A mapping: rows rA and rA+4, j's jsub..jsub+3
    const int rA   = lane >> 4;
    const int jsub = (lane & 15) * 4;
    const float a0 = wh1[rw + rA];
    const float a4 = wh1[rw + rA + 4];
    const float M0 = M[rw + rA];
    const float M4 = M[rw + rA + 4];

    // phase B mapping: rowgroup g (4 rows), f-pair fp
    const int g  = lane >> 5;
    const int fp = lane & 31;

    float2 o0 = {0.f, 0.f}, o1 = {0.f, 0.f}, o2 = {0.f, 0.f}, o3 = {0.f, 0.f};
    float l0 = 0.f, l4 = 0.f;

    {   // stage tile 0
        const float4* src = (const float4*)(Wh + (size_t)j0 * GAT_F);
#pragma unroll
        for (int c = 0; c < 4; ++c)
            ((float4*)sWh[0])[tid + c * 256] = src[tid + c * 256];
    }

    for (int t = 0; t < NTILES; ++t) {
        const int cur = t & 1;
        __syncthreads();   // stage(cur) visible; prev phase B done with cur^1
        if (t + 1 < NTILES) {
            const float4* src = (const float4*)(Wh + (size_t)(j0 + (t + 1) * TJ) * GAT_F);
#pragma unroll
            for (int c = 0; c < 4; ++c)
                ((float4*)sWh[cur ^ 1])[tid + c * 256] = src[tid + c * 256];
        }

        // ---- phase A: scores -> p (wave-private sP, no barrier needed)
        const int jt = j0 + t * TJ;
        const int4 ad0 = *(const int4*)&adj[(size_t)(rw + rA) * GAT_N + jt + jsub];
        const int4 ad4 = *(const int4*)&adj[(size_t)(rw + rA + 4) * GAT_N + jt + jsub];
        const float4 b4 = *(const float4*)&wh2[jt + jsub];
        float4 p0, p4;
        p0.x = ad0.x > 0 ? __expf(lrelu(a0 + b4.x) - M0) : 0.f;
        p0.y = ad0.y > 0 ? __expf(lrelu(a0 + b4.y) - M0) : 0.f;
        p0.z = ad0.z > 0 ? __expf(lrelu(a0 + b4.z) - M0) : 0.f;
        p0.w = ad0.w > 0 ? __expf(lrelu(a0 + b4.w) - M0) : 0.f;
        p4.x = ad4.x > 0 ? __expf(lrelu(a4 + b4.x) - M4) : 0.f;
        p4.y = ad4.y > 0 ? __expf(lrelu(a4 + b4.y) - M4) : 0.f;
        p4.z = ad4.z > 0 ? __expf(lrelu(a4 + b4.z) - M4) : 0.f;
        p4.w = ad4.w > 0 ? __expf(lrelu(a4 + b4.w) - M4) : 0.f;
        l0 += p0.x + p0.y + p0.z + p0.w;
        l4 += p4.x + p4.y + p4.z + p4.w;
        *(float4*)&sP[w][rA][jsub]     = p0;
        *(float4*)&sP[w][rA + 4][jsub] = p4;
        __builtin_amdgcn_wave_barrier();   // keep A-writes before B-reads (same wave, in-order DS)

        // ---- phase B: o += P(8x64) @ sWh(64x64), lane = (g, fp)
        const float* sp0 = sP[w][g * 4 + 0];
        const float* sp1 = sP[w][g * 4 + 1];
        const float* sp2 = sP[w][g * 4 + 2];
        const float* sp3 = sP[w][g * 4 + 3];
        const float* swc = sWh[cur];
#pragma unroll
        for (int jj = 0; jj < TJ; jj += 4) {
            float4 pr0 = *(const float4*)&sp0[jj];
            float4 pr1 = *(const float4*)&sp1[jj];
            float4 pr2 = *(const float4*)&sp2[jj];
            float4 pr3 = *(const float4*)&sp3[jj];
            const float* pr0f = (const float*)&pr0;
            const float* pr1f = (const float*)&pr1;
            const float* pr2f = (const float*)&pr2;
            const float* pr3f = (const float*)&pr3;
#pragma unroll
            for (int c = 0; c < 4; ++c) {
                const float2 whv = *(const float2*)&swc[(jj + c) * GAT_F + fp * 2];
                o0.x += pr0f[c] * whv.x;  o0.y += pr0f[c] * whv.y;
                o1.x += pr1f[c] * whv.x;  o1.y += pr1f[c] * whv.y;
                o2.x += pr2f[c] * whv.x;  o2.y += pr2f[c] * whv.y;
                o3.x += pr3f[c] * whv.x;  o3.y += pr3f[c] * whv.y;
            }
        }
    }

    // ---- epilogue: l reduce within 16-lane groups; write partials
#pragma unroll
    for (int m = 1; m < 16; m <<= 1) {
        l0 += __shfl_xor(l0, m);
        l4 += __shfl_xor(l4, m);
    }
    if ((lane & 15) == 0) {
        pl[(size_t)blockIdx.y * GAT_N + rw + rA]     = l0;
        pl[(size_t)blockIdx.y * GAT_N + rw + rA + 4] = l4;
    }
    const size_t obase = ((size_t)blockIdx.y * GAT_N + rw + g * 4) * GAT_F + fp * 2;
    *(float2*)&po[obase + 0 * GAT_F] = o0;
    *(float2*)&po[obase + 1 * GAT_F] = o1;
    *(float2*)&po[obase + 2 * GAT_F] = o2;
    *(float2*)&po[obase + 3 * GAT_F] = o3;
}

// ---------------------------------------------------------------- kernel 4
__global__ __launch_bounds__(256) void k_merge(
    const float* __restrict__ po, const float* __restrict__ pl,
    float* __restrict__ out)
{
    const int idx = blockIdx.x * 256 + threadIdx.x;   // = i*64 + f
    const int i = idx >> 6;
    float s = 0.f, ls = 0.f;
#pragma unroll
    for (int y = 0; y < JSPLIT; ++y) {
        s  += po[(size_t)y * GAT_N * GAT_F + idx];
        ls += pl[(size_t)y * GAT_N + i];
    }
    out[idx] = s / ls;
}

// ---------------------------------------------------------------- launch
extern "C" void kernel_launch(void* const* d_in, const int* in_sizes, int n_in,
                              void* d_out, int out_size, void* d_ws, size_t ws_size,
                              hipStream_t stream) {
    (void)in_sizes; (void)n_in; (void)out_size; (void)ws_size;
    const float* h   = (const float*)d_in[0];
    const int*   adj = (const int*)d_in[1];
    const float* W   = (const float*)d_in[2];
    const float* a   = (const float*)d_in[3];
    float* out = (float*)d_out;

    float* ws  = (float*)d_ws;
    float* Wh  = ws;                    // 524288
    float* wh1 = ws + 524288;           // 8192
    float* wh2 = ws + 532480;           // 8192
    float* M   = ws + 540672;           // 8192
    float* po  = ws + 548864;           // 4*8192*64 = 2097152
    float* pl  = ws + 2646016;          // 4*8192   = 32768 ; total 2678784 floats

    k_wh    <<<GAT_N / 16, 256, 0, stream>>>(h, W, a, Wh, wh1, wh2);
    k_mrow  <<<1,          256, 0, stream>>>(wh1, wh2, M);
    k_attend<<<dim3(GAT_N / 32, JSPLIT), 256, 0, stream>>>(adj, Wh, wh1, wh2, M, po, pl);
    k_merge <<<GAT_N * GAT_F / 256, 256, 0, stream>>>(po, pl, out);
}